// Round 1
// baseline (1068.445 us; speedup 1.0000x reference)
//
#include <hip/hip_runtime.h>
#include <hip/hip_bf16.h>

// Tucker-decomposed 3x3 conv:
//   out = last @ conv3x3(core, first @ x) + bias
// Shapes: x[32,256,56,56], first[64,256], core[64,64,3,3], last[256,64], bias[256]
// Three-stage factored execution: 14 GFLOP instead of 118 GFLOP full conv.

#define B_    32
#define CIN_  256
#define H_    56
#define W_    56
#define HW_   (H_ * W_)        // 3136
#define COUT_ 256
#define S_    64               // IN_RANK
#define R_    64               // OUT_RANK
#define BHW_  (B_ * HW_)       // 100352 = 392 * 256

// Workspace layout (floats):
//   firstT [CIN_][S_]          at 0         (16384)
//   coreT  [S_*9][R_]          at 16384     (36864)
//   x1     [B_][S_][HW_]       at 53248     (6422528)
//   y1     [B_][R_][HW_]       at 6475776   (6422528)
#define WS_FIRSTT 0
#define WS_CORET  16384
#define WS_X1     53248
#define WS_Y1     6475776

// ---- prep: transpose factors so coefficient reads are contiguous ----
__global__ __launch_bounds__(256) void prep_kernel(
    const float* __restrict__ first,  // [S_][CIN_]
    const float* __restrict__ core,   // [R_][S_][3][3]
    float* __restrict__ ws) {
  int i = blockIdx.x * 256 + threadIdx.x;   // 53248 threads
  if (i < 16384) {
    // firstT[c][s] = first[s][c]
    int c = i >> 6, s = i & 63;
    ws[WS_FIRSTT + i] = first[s * CIN_ + c];
  } else {
    // coreT[s*9+t][r] = core[r][s*9+t]
    int j = i - 16384;
    int st = j >> 6, r = j & 63;
    ws[WS_CORET + j] = core[r * (S_ * 9) + st];
  }
}

// ---- stage A: x1[b,s,hw] = sum_c firstT[c][s] * x[b,c,hw] ----
__global__ __launch_bounds__(256) void stageA_kernel(
    const float* __restrict__ x,
    const float* __restrict__ firstT,
    float* __restrict__ x1) {
  int idx = blockIdx.x * 256 + threadIdx.x;   // < 100352
  int b  = idx / HW_;
  int hw = idx - b * HW_;
  const float* xp = x + (size_t)b * (CIN_ * HW_) + hw;

  float acc[S_];
#pragma unroll
  for (int s = 0; s < S_; ++s) acc[s] = 0.f;

  for (int c = 0; c < CIN_; ++c) {
    float xv = xp[(size_t)c * HW_];
    const float4* f4 = (const float4*)(firstT + c * S_);   // wave-uniform -> s_load
#pragma unroll
    for (int j = 0; j < S_ / 4; ++j) {
      float4 f = f4[j];
      acc[4 * j + 0] += f.x * xv;
      acc[4 * j + 1] += f.y * xv;
      acc[4 * j + 2] += f.z * xv;
      acc[4 * j + 3] += f.w * xv;
    }
  }

  float* o = x1 + (size_t)b * (S_ * HW_) + hw;
#pragma unroll
  for (int s = 0; s < S_; ++s) o[(size_t)s * HW_] = acc[s];
}

// ---- stage B: y1[b,r,hw] = sum_{s,kh,kw} coreT[s*9+t][r] * x1[b,s,hh,ww] ----
__global__ __launch_bounds__(256) void stageB_kernel(
    const float* __restrict__ x1,
    const float* __restrict__ coreT,
    float* __restrict__ y1) {
  int idx = blockIdx.x * 256 + threadIdx.x;   // < 100352
  int b  = idx / HW_;
  int hw = idx - b * HW_;
  int h  = hw / W_;
  int w  = hw - h * W_;
  const float* xp = x1 + (size_t)b * (S_ * HW_);

  float acc[R_];
#pragma unroll
  for (int r = 0; r < R_; ++r) acc[r] = 0.f;

  for (int s = 0; s < S_; ++s) {
    const float* xs = xp + s * HW_;
#pragma unroll
    for (int kh = 0; kh < 3; ++kh) {
      int hh = h + kh - 1;
      bool rowok = ((unsigned)hh < (unsigned)H_);
#pragma unroll
      for (int kw = 0; kw < 3; ++kw) {
        int ww = w + kw - 1;
        bool ok = rowok && ((unsigned)ww < (unsigned)W_);
        float xv = ok ? xs[hh * W_ + ww] : 0.f;
        const float4* c4 = (const float4*)(coreT + (s * 9 + kh * 3 + kw) * R_);
#pragma unroll
        for (int j = 0; j < R_ / 4; ++j) {
          float4 f = c4[j];
          acc[4 * j + 0] += f.x * xv;
          acc[4 * j + 1] += f.y * xv;
          acc[4 * j + 2] += f.z * xv;
          acc[4 * j + 3] += f.w * xv;
        }
      }
    }
  }

  float* o = y1 + (size_t)b * (R_ * HW_) + hw;
#pragma unroll
  for (int r = 0; r < R_; ++r) o[(size_t)r * HW_] = acc[r];
}

// ---- stage C: out[b,o,hw] = bias[o] + sum_r last[o][r] * y1[b,r,hw] ----
__global__ __launch_bounds__(256) void stageC_kernel(
    const float* __restrict__ y1,
    const float* __restrict__ last,   // [COUT_][R_] (r contiguous already)
    const float* __restrict__ bias,
    float* __restrict__ out) {
  int idx = blockIdx.x * 256 + threadIdx.x;   // < 100352
  int b  = idx / HW_;
  int hw = idx - b * HW_;
  const float* yp = y1 + (size_t)b * (R_ * HW_) + hw;

  float yv[R_];
#pragma unroll
  for (int r = 0; r < R_; ++r) yv[r] = yp[(size_t)r * HW_];

  float* op = out + (size_t)b * (COUT_ * HW_) + hw;
  for (int o = 0; o < COUT_; ++o) {
    float a = bias[o];                                     // wave-uniform -> s_load
    const float4* l4 = (const float4*)(last + o * R_);     // wave-uniform -> s_load
#pragma unroll
    for (int j = 0; j < R_ / 4; ++j) {
      float4 f = l4[j];
      a += f.x * yv[4 * j + 0];
      a += f.y * yv[4 * j + 1];
      a += f.z * yv[4 * j + 2];
      a += f.w * yv[4 * j + 3];
    }
    op[(size_t)o * HW_] = a;
  }
}

extern "C" void kernel_launch(void* const* d_in, const int* in_sizes, int n_in,
                              void* d_out, int out_size, void* d_ws, size_t ws_size,
                              hipStream_t stream) {
  const float* x     = (const float*)d_in[0];
  const float* first = (const float*)d_in[1];
  const float* core  = (const float*)d_in[2];
  const float* last  = (const float*)d_in[3];
  const float* bias  = (const float*)d_in[4];
  float* out = (float*)d_out;
  float* ws  = (float*)d_ws;

  float* firstT = ws + WS_FIRSTT;
  float* coreT  = ws + WS_CORET;
  float* x1     = ws + WS_X1;
  float* y1     = ws + WS_Y1;

  prep_kernel<<<208, 256, 0, stream>>>(first, core, ws);
  stageA_kernel<<<BHW_ / 256, 256, 0, stream>>>(x, firstT, x1);
  stageB_kernel<<<BHW_ / 256, 256, 0, stream>>>(x1, coreT, y1);
  stageC_kernel<<<BHW_ / 256, 256, 0, stream>>>(y1, last, bias, out);
}

// Round 2
// 334.733 us; speedup vs baseline: 3.1919x; 3.1919x over previous
//
#include <hip/hip_runtime.h>
#include <hip/hip_bf16.h>

// Tucker conv via 3 bf16-MFMA GEMM stages with rank-innermost padded layouts.
//   x1p[b][h'=58][w'=64][s=64]  (h'/w' shifted +1, zero halo via memset)
//   y1p[b][h=56][w=64][r=64]    (w 56..63 garbage, masked at stage C store)
// Stage B = 9 shift-offset GEMMs over the padded layout (no bounds logic).

typedef __attribute__((ext_vector_type(8))) short short8;
typedef __attribute__((ext_vector_type(4))) short short4v;
typedef __attribute__((ext_vector_type(4))) float f32x4;

#define B_    32
#define CIN_  256
#define H_    56
#define W_    56
#define HW_   (H_*W_)          // 3136
#define COUT_ 256
#define S_    64
#define R_    64
#define HP_   58
#define WP_   64

// workspace byte offsets (all 16B-aligned)
#define OFF_FIRSTW  0u                        // bf16 [64][256]      32768 B
#define OFF_COREW   32768u                    // bf16 [9][64][64]    73728 B
#define OFF_LASTW   106496u                   // bf16 [256][64]      32768 B
#define OFF_X1P     139264u                   // bf16 [32][58][64][64] 15204352 B (+1024 slack)
#define X1P_BYTES   15204352u
#define OFF_Y1P     (OFF_X1P + X1P_BYTES + 1024u)  // bf16 [32][56][64][64] 14680064 B

__device__ __forceinline__ unsigned short f2bf(float f) {
  union { float f; unsigned int u; } v; v.f = f;
  unsigned int r = (v.u + 0x7FFFu + ((v.u >> 16) & 1u)) >> 16;
  return (unsigned short)r;
}

__device__ __forceinline__ short4v pack4(f32x4 a) {
  short4v p;
  p.x = (short)f2bf(a.x); p.y = (short)f2bf(a.y);
  p.z = (short)f2bf(a.z); p.w = (short)f2bf(a.w);
  return p;
}

// ---- prep: cast/transpose the small factors to bf16 layouts ----
__global__ __launch_bounds__(256) void prep_kernel(
    const float* __restrict__ first,   // [64][256]
    const float* __restrict__ core,    // [64][64][3][3]
    const float* __restrict__ last,    // [256][64]
    unsigned short* __restrict__ ws16) {
  int i = blockIdx.x * 256 + threadIdx.x;   // 69632 threads
  if (i < 16384) {
    ws16[(OFF_FIRSTW >> 1) + i] = f2bf(first[i]);                 // [s][c] row-major
  } else if (i < 53248) {
    int j = i - 16384;                                            // coreW[t][r][s]
    int t = j >> 12, r = (j >> 6) & 63, s = j & 63;
    ws16[(OFF_COREW >> 1) + j] = f2bf(core[(r * 64 + s) * 9 + t]);
  } else {
    int j = i - 53248;
    ws16[(OFF_LASTW >> 1) + j] = f2bf(last[j]);                   // [o][r] row-major
  }
}

// ---- stage A: x1p[b,h+1,w+1,s] = sum_c first[s,c] * x[b,c,h,w] ----
__global__ __launch_bounds__(256) void stageA_kernel(
    const float* __restrict__ x,
    const unsigned short* __restrict__ ws16) {
  const unsigned short* firstW = ws16 + (OFF_FIRSTW >> 1);
  unsigned short* x1p = (unsigned short*)ws16 + (OFF_X1P >> 1);

  int tid = threadIdx.x, wave = tid >> 6, lane = tid & 63;
  int quad = lane >> 4, l15 = lane & 15;
  int bh = blockIdx.x;                 // 0..1791
  int b = bh / H_, h = bh - b * H_;
  int w = wave * 16 + l15;             // 0..63
  int wx = w < 55 ? w : 55;            // clamp reads (cols >=56 are masked later)

  const float* xb = x + (size_t)b * (CIN_ * HW_) + h * W_ + wx;

  f32x4 acc[4] = {{0.f,0.f,0.f,0.f},{0.f,0.f,0.f,0.f},{0.f,0.f,0.f,0.f},{0.f,0.f,0.f,0.f}};

#pragma unroll
  for (int k0 = 0; k0 < CIN_; k0 += 32) {
    const float* xc = xb + (size_t)(k0 + quad * 8) * HW_;
    float bv[8];
#pragma unroll
    for (int j = 0; j < 8; ++j) bv[j] = xc[(size_t)j * HW_];
    short8 bfrag;
#pragma unroll
    for (int j = 0; j < 8; ++j) bfrag[j] = (short)f2bf(bv[j]);
#pragma unroll
    for (int mt = 0; mt < 4; ++mt) {
      short8 af = *(const short8*)(firstW + (mt * 16 + l15) * CIN_ + k0 + quad * 8);
      acc[mt] = __builtin_amdgcn_mfma_f32_16x16x32_bf16(af, bfrag, acc[mt], 0, 0, 0);
    }
  }

  if (w < W_) {
    size_t base = (((size_t)(b * HP_ + h + 1) * WP_) + (w + 1)) * 64 + quad * 4;
#pragma unroll
    for (int mt = 0; mt < 4; ++mt)
      *(short4v*)(x1p + base + mt * 16) = pack4(acc[mt]);
  }
}

// ---- stage B: y1p[b,h,w,r] = sum_{kh,kw,s} core[r,s,kh,kw] * x1p[b,h+kh,w+kw,s] ----
__global__ __launch_bounds__(256) void stageB_kernel(
    const unsigned short* __restrict__ ws16) {
  const unsigned short* coreW = ws16 + (OFF_COREW >> 1);
  const unsigned short* x1p   = ws16 + (OFF_X1P >> 1);
  unsigned short* y1p = (unsigned short*)ws16 + (OFF_Y1P >> 1);

  int tid = threadIdx.x, wave = tid >> 6, lane = tid & 63;
  int quad = lane >> 4, l15 = lane & 15;
  int bh = blockIdx.x;
  int b = bh / H_, h = bh - b * H_;
  int w = wave * 16 + l15;             // 0..63

  f32x4 acc[4] = {{0.f,0.f,0.f,0.f},{0.f,0.f,0.f,0.f},{0.f,0.f,0.f,0.f},{0.f,0.f,0.f,0.f}};

#pragma unroll
  for (int kh = 0; kh < 3; ++kh) {
#pragma unroll
    for (int kw = 0; kw < 3; ++kw) {
      int t = kh * 3 + kw;
      const unsigned short* xs =
          x1p + (((size_t)(b * HP_ + h + kh) * WP_) + (w + kw)) * 64;
#pragma unroll
      for (int k0 = 0; k0 < 64; k0 += 32) {
        short8 bfrag = *(const short8*)(xs + k0 + quad * 8);
#pragma unroll
        for (int mt = 0; mt < 4; ++mt) {
          short8 af = *(const short8*)(coreW + ((t * 64 + mt * 16 + l15) << 6) + k0 + quad * 8);
          acc[mt] = __builtin_amdgcn_mfma_f32_16x16x32_bf16(af, bfrag, acc[mt], 0, 0, 0);
        }
      }
    }
  }

  if (w < W_) {
    size_t base = (((size_t)(b * H_ + h) * WP_) + w) * 64 + quad * 4;
#pragma unroll
    for (int mt = 0; mt < 4; ++mt)
      *(short4v*)(y1p + base + mt * 16) = pack4(acc[mt]);
  }
}

// ---- stage C: out[b,o,h,w] = bias[o] + sum_r last[o,r] * y1p[b,h,w,r] ----
__global__ __launch_bounds__(256) void stageC_kernel(
    const unsigned short* __restrict__ ws16,
    const float* __restrict__ bias,
    float* __restrict__ out) {
  const unsigned short* lastW = ws16 + (OFF_LASTW >> 1);
  const unsigned short* y1p   = ws16 + (OFF_Y1P >> 1);

  int tid = threadIdx.x, wave = tid >> 6, lane = tid & 63;
  int quad = lane >> 4, l15 = lane & 15;
  int bh = blockIdx.x;
  int b = bh / H_, h = bh - b * H_;
  int w = wave * 16 + l15;             // 0..63

  f32x4 acc[16];
#pragma unroll
  for (int mt = 0; mt < 16; ++mt) acc[mt] = (f32x4){0.f,0.f,0.f,0.f};

  const unsigned short* yb = y1p + (((size_t)(b * H_ + h) * WP_) + w) * 64;
#pragma unroll
  for (int k0 = 0; k0 < 64; k0 += 32) {
    short8 bfrag = *(const short8*)(yb + k0 + quad * 8);
#pragma unroll
    for (int mt = 0; mt < 16; ++mt) {
      short8 af = *(const short8*)(lastW + (mt * 16 + l15) * 64 + k0 + quad * 8);
      acc[mt] = __builtin_amdgcn_mfma_f32_16x16x32_bf16(af, bfrag, acc[mt], 0, 0, 0);
    }
  }

  if (w < W_) {
    float* ob = out + (size_t)b * (COUT_ * HW_) + h * W_ + w;
#pragma unroll
    for (int mt = 0; mt < 16; ++mt) {
      float4 bv = *(const float4*)(bias + mt * 16 + quad * 4);
      int o = mt * 16 + quad * 4;
      ob[(size_t)(o + 0) * HW_] = acc[mt].x + bv.x;
      ob[(size_t)(o + 1) * HW_] = acc[mt].y + bv.y;
      ob[(size_t)(o + 2) * HW_] = acc[mt].z + bv.z;
      ob[(size_t)(o + 3) * HW_] = acc[mt].w + bv.w;
    }
  }
}

extern "C" void kernel_launch(void* const* d_in, const int* in_sizes, int n_in,
                              void* d_out, int out_size, void* d_ws, size_t ws_size,
                              hipStream_t stream) {
  const float* x     = (const float*)d_in[0];
  const float* first = (const float*)d_in[1];
  const float* core  = (const float*)d_in[2];
  const float* last  = (const float*)d_in[3];
  const float* bias  = (const float*)d_in[4];
  float* out = (float*)d_out;
  unsigned short* ws16 = (unsigned short*)d_ws;

  // zero the padded x1 tensor (halo must be 0); graph-capture-safe async memset
  hipMemsetAsync((char*)d_ws + OFF_X1P, 0, X1P_BYTES + 1024, stream);

  prep_kernel<<<272, 256, 0, stream>>>(first, core, last, ws16);
  stageA_kernel<<<B_ * H_, 256, 0, stream>>>(x, ws16);
  stageB_kernel<<<B_ * H_, 256, 0, stream>>>(ws16);
  stageC_kernel<<<B_ * H_, 256, 0, stream>>>(ws16, bias, out);
}

// Round 3
// 330.291 us; speedup vs baseline: 3.2349x; 1.0134x over previous
//
#include <hip/hip_runtime.h>
#include <hip/hip_bf16.h>

// Tucker conv, 2-kernel MFMA pipeline:
//   stageA: x[b,c,h,w] -> x1p[b,h'=h+1,w'=w+1,s]  (bf16, rank-innermost, halos
//           written as true zeros by the kernel itself — no memset)
//   fusedBC: per (b,h): LDS-stage 3 x1p rows, 9-offset core GEMM (r=64),
//           wave-local LDS transpose, expand GEMM (o=256) + bias -> out.

typedef __attribute__((ext_vector_type(8))) short short8;
typedef __attribute__((ext_vector_type(4))) short short4v;
typedef __attribute__((ext_vector_type(4))) float f32x4;

#define B_    32
#define CIN_  256
#define H_    56
#define W_    56
#define HW_   (H_*W_)          // 3136
#define COUT_ 256
#define HP_   58
#define WP_   64

// workspace byte offsets (16B-aligned)
#define OFF_FIRSTW  0u                        // bf16 [64][256]        32768 B
#define OFF_COREW   32768u                    // bf16 [9][64][64]      73728 B
#define OFF_LASTW   106496u                   // bf16 [256][64]        32768 B
#define OFF_X1P     139264u                   // bf16 [32][58][64][64] 15204352 B (+1KB slack)

__device__ __forceinline__ unsigned short f2bf(float f) {
  union { float f; unsigned int u; } v; v.f = f;
  return (unsigned short)((v.u + 0x7FFFu + ((v.u >> 16) & 1u)) >> 16);
}
__device__ __forceinline__ short4v pack4(f32x4 a) {
  short4v p;
  p.x = (short)f2bf(a.x); p.y = (short)f2bf(a.y);
  p.z = (short)f2bf(a.z); p.w = (short)f2bf(a.w);
  return p;
}

// ---- prep: cast/transpose small factors to bf16 ----
__global__ __launch_bounds__(256) void prep_kernel(
    const float* __restrict__ first,   // [64][256]
    const float* __restrict__ core,    // [64][64][3][3]
    const float* __restrict__ last,    // [256][64]
    unsigned short* __restrict__ ws16) {
  int i = blockIdx.x * 256 + threadIdx.x;   // 69632 threads
  if (i < 16384) {
    ws16[(OFF_FIRSTW >> 1) + i] = f2bf(first[i]);                 // [s][c]
  } else if (i < 53248) {
    int j = i - 16384;                                            // coreW[t][r][s]
    int t = j >> 12, r = (j >> 6) & 63, s = j & 63;
    ws16[(OFF_COREW >> 1) + j] = f2bf(core[(r * 64 + s) * 9 + t]);
  } else {
    ws16[(OFF_LASTW >> 1) + (i - 53248)] = f2bf(last[i - 53248]); // [o][r]
  }
}

// ---- stage A: one block per (b, h'); LDS-staged GEMM M=64(s) K=256(c) N=64(w') ----
#define ATS 36   // LDS halfs per w'-entry (32 c + 4 pad); stride 72 B -> even-bank, conflict-free b64 reads
__global__ __launch_bounds__(256) void stageA_kernel(
    const float* __restrict__ x,
    unsigned short* __restrict__ ws16) {
  __shared__ unsigned short tile[64 * ATS];   // 4608 B
  const unsigned short* firstW = ws16 + (OFF_FIRSTW >> 1);
  unsigned short* x1p = ws16 + (OFF_X1P >> 1);

  int tid = threadIdx.x, wave = tid >> 6, lane = tid & 63;
  int quad = lane >> 4, l15 = lane & 15;
  int bid = blockIdx.x;                 // 32*58
  int b = bid / HP_, hp = bid - b * HP_;
  size_t rowbase = (size_t)(b * HP_ + hp) * (WP_ * 64);

  if (hp == 0 || hp == HP_ - 1) {       // halo rows: true zeros
    short8 z = {0,0,0,0,0,0,0,0};
#pragma unroll
    for (int i = 0; i < 2; ++i)
      *(short8*)(x1p + rowbase + (size_t)(tid + i * 256) * 8) = z;
    return;
  }

  int h = hp - 1;
  int c_off = tid >> 3;                 // 0..31
  int w0 = (tid & 7) * 8;               // 0,8,...,56
  int wp = wave * 16 + l15;             // w' handled by this lane: 0..63
  const float* xrow = x + (size_t)b * (CIN_ * HW_) + h * W_;

  f32x4 acc[4] = {{0,0,0,0},{0,0,0,0},{0,0,0,0},{0,0,0,0}};

  for (int c0 = 0; c0 < CIN_; c0 += 32) {
    // ---- stage 32 c-rows into LDS as [w'][c] bf16 (w' = w+1 shift, halo zeros)
    if (w0 < 56) {
      const float* p = xrow + (size_t)(c0 + c_off) * HW_ + w0;
      float4 v0 = *(const float4*)p;
      float4 v1 = *(const float4*)(p + 4);
      tile[(w0 + 1) * ATS + c_off] = f2bf(v0.x);
      tile[(w0 + 2) * ATS + c_off] = f2bf(v0.y);
      tile[(w0 + 3) * ATS + c_off] = f2bf(v0.z);
      tile[(w0 + 4) * ATS + c_off] = f2bf(v0.w);
      tile[(w0 + 5) * ATS + c_off] = f2bf(v1.x);
      tile[(w0 + 6) * ATS + c_off] = f2bf(v1.y);
      tile[(w0 + 7) * ATS + c_off] = f2bf(v1.z);
      tile[(w0 + 8) * ATS + c_off] = f2bf(v1.w);
    } else {                            // w0==56: zero w'=57..63 and w'=0
#pragma unroll
      for (int j = 0; j < 7; ++j) tile[(57 + j) * ATS + c_off] = 0;
      tile[c_off] = 0;
    }
    __syncthreads();
    // ---- MFMA: bfrag from LDS (2x ds_read_b64), A-frags from firstW (L1-hot)
    short4v blo = *(const short4v*)&tile[wp * ATS + quad * 8];
    short4v bhi = *(const short4v*)&tile[wp * ATS + quad * 8 + 4];
    short8 bfrag = {blo.x, blo.y, blo.z, blo.w, bhi.x, bhi.y, bhi.z, bhi.w};
#pragma unroll
    for (int mt = 0; mt < 4; ++mt) {
      short8 af = *(const short8*)(firstW + (mt * 16 + l15) * CIN_ + c0 + quad * 8);
      acc[mt] = __builtin_amdgcn_mfma_f32_16x16x32_bf16(af, bfrag, acc[mt], 0, 0, 0);
    }
    __syncthreads();
  }
  // store: x1p[b,hp,w',s]; s = mt*16 + quad*4 + reg (D-layout), w' per-lane
#pragma unroll
  for (int mt = 0; mt < 4; ++mt)
    *(short4v*)(x1p + rowbase + (size_t)wp * 64 + mt * 16 + quad * 4) = pack4(acc[mt]);
}

// ---- fused B+C: one block per (b, h) ----
#define XTS 72            // LDS halfs per w'-entry (64 s + 8 pad); 144 B stride
#define XTROW (66 * XTS)  // 4752 halfs per staged row
__global__ __launch_bounds__(256) void fusedBC_kernel(
    const unsigned short* __restrict__ ws16,
    const float* __restrict__ bias,
    float* __restrict__ out) {
  __shared__ unsigned short xt[3 * XTROW];  // 28512 B
  __shared__ unsigned short yt[64 * XTS];   //  9216 B
  const unsigned short* coreW = ws16 + (OFF_COREW >> 1);
  const unsigned short* lastW = ws16 + (OFF_LASTW >> 1);
  const unsigned short* x1p   = ws16 + (OFF_X1P >> 1);

  int tid = threadIdx.x, wave = tid >> 6, lane = tid & 63;
  int quad = lane >> 4, l15 = lane & 15;
  int bid = blockIdx.x;                 // 32*56
  int b = bid / H_, h = bid - b * H_;
  int w = wave * 16 + l15;              // 0..63 (w>=56 garbage, masked at store)

  // ---- stage 3 x1p rows (h..h+2), 66 w'-entries each (2-entry spill is
  //      garbage feeding only masked lanes; x1p has slack at the end)
  for (int i = tid; i < 3 * 66 * 8; i += 256) {
    int row = i / 528, rem = i - row * 528;
    int wp = rem >> 3, oct = rem & 7;
    short8 v = *(const short8*)(x1p + (size_t)(b * HP_ + h + row) * (WP_ * 64)
                                + (size_t)wp * 64 + oct * 8);
    *(short8*)&xt[(row * 66 + wp) * XTS + oct * 8] = v;
  }
  __syncthreads();

  // ---- B-phase: y1[r=64][w] = sum_{t,s} core * x1  (acc rows r, cols w)
  f32x4 acc[4] = {{0,0,0,0},{0,0,0,0},{0,0,0,0},{0,0,0,0}};
#pragma unroll
  for (int kh = 0; kh < 3; ++kh) {
#pragma unroll
    for (int kw = 0; kw < 3; ++kw) {
      int t = kh * 3 + kw;
      int base = (kh * 66 + w + kw) * XTS;
#pragma unroll
      for (int k0 = 0; k0 < 64; k0 += 32) {
        short8 bfrag = *(const short8*)&xt[base + k0 + quad * 8];
#pragma unroll
        for (int mt = 0; mt < 4; ++mt) {
          short8 af = *(const short8*)(coreW + (t * 64 + mt * 16 + l15) * 64 + k0 + quad * 8);
          acc[mt] = __builtin_amdgcn_mfma_f32_16x16x32_bf16(af, bfrag, acc[mt], 0, 0, 0);
        }
      }
    }
  }

  // ---- wave-local transpose through LDS: yt[w][r]  (each wave touches only
  //      its own w-columns -> no barrier needed)
#pragma unroll
  for (int mt = 0; mt < 4; ++mt)
    *(short4v*)&yt[w * XTS + mt * 16 + quad * 4] = pack4(acc[mt]);

  // ---- C-phase: out[o=256][w] = bias + last @ y1
  f32x4 acc2[16];
#pragma unroll
  for (int mt = 0; mt < 16; ++mt) acc2[mt] = (f32x4){0, 0, 0, 0};
#pragma unroll
  for (int k0 = 0; k0 < 64; k0 += 32) {
    short8 bfrag = *(const short8*)&yt[w * XTS + k0 + quad * 8];
#pragma unroll
    for (int mt = 0; mt < 16; ++mt) {
      short8 af = *(const short8*)(lastW + (mt * 16 + l15) * 64 + k0 + quad * 8);
      acc2[mt] = __builtin_amdgcn_mfma_f32_16x16x32_bf16(af, bfrag, acc2[mt], 0, 0, 0);
    }
  }

  if (w < W_) {
    float* ob = out + (size_t)b * (COUT_ * HW_) + h * W_ + w;
#pragma unroll
    for (int mt = 0; mt < 16; ++mt) {
      float4 bv = *(const float4*)(bias + mt * 16 + quad * 4);
      int o = mt * 16 + quad * 4;
      ob[(size_t)(o + 0) * HW_] = acc2[mt].x + bv.x;
      ob[(size_t)(o + 1) * HW_] = acc2[mt].y + bv.y;
      ob[(size_t)(o + 2) * HW_] = acc2[mt].z + bv.z;
      ob[(size_t)(o + 3) * HW_] = acc2[mt].w + bv.w;
    }
  }
}

extern "C" void kernel_launch(void* const* d_in, const int* in_sizes, int n_in,
                              void* d_out, int out_size, void* d_ws, size_t ws_size,
                              hipStream_t stream) {
  const float* x     = (const float*)d_in[0];
  const float* first = (const float*)d_in[1];
  const float* core  = (const float*)d_in[2];
  const float* last  = (const float*)d_in[3];
  const float* bias  = (const float*)d_in[4];
  float* out = (float*)d_out;
  unsigned short* ws16 = (unsigned short*)d_ws;

  prep_kernel<<<272, 256, 0, stream>>>(first, core, last, ws16);
  stageA_kernel<<<B_ * HP_, 256, 0, stream>>>(x, ws16);
  fusedBC_kernel<<<B_ * H_, 256, 0, stream>>>(ws16, bias, out);
}